// Round 7
// baseline (238.316 us; speedup 1.0000x reference)
//
#include <hip/hip_runtime.h>
#include <hip/hip_bf16.h>

#define BB 2
#define SEQ 2048
#define NHEAD 8
#define HD 64
#define ATT_T 1e-4f
#define QSCALE 0.18033688011112042f  // 0.125 * log2(e): scores in log2 domain

typedef short s16x8 __attribute__((ext_vector_type(8)));
typedef float f32x16 __attribute__((ext_vector_type(16)));

#define MFMA32(a, b, c) __builtin_amdgcn_mfma_f32_32x32x16_bf16((a), (b), (c), 0, 0, 0)
#define EXP2(x) __builtin_amdgcn_exp2f(x)

__device__ __forceinline__ unsigned short bfr(float x) {
  __hip_bfloat16 h = __float2bfloat16(x);
  return __builtin_bit_cast(unsigned short, h);
}
__device__ __forceinline__ unsigned int packbf(float a, float b) {
  return (unsigned int)bfr(a) | ((unsigned int)bfr(b) << 16);
}

// ---------------------------------------------------------------------------
// Transpose-convert: WT[n][k] = bf16(W[k][n]), 512x512, 4 matrices batched.
// ---------------------------------------------------------------------------
__global__ __launch_bounds__(256) void convT(const float* __restrict__ w0,
                                             const float* __restrict__ w1,
                                             const float* __restrict__ w2,
                                             const float* __restrict__ w3,
                                             unsigned short* __restrict__ o0,
                                             unsigned short* __restrict__ o1,
                                             unsigned short* __restrict__ o2,
                                             unsigned short* __restrict__ o3) {
  __shared__ float tle[64][65];
  const float* W = blockIdx.z == 0 ? w0 : blockIdx.z == 1 ? w1 : blockIdx.z == 2 ? w2 : w3;
  unsigned short* WT = blockIdx.z == 0 ? o0 : blockIdx.z == 1 ? o1 : blockIdx.z == 2 ? o2 : o3;
  const int r0 = blockIdx.y * 64, c0 = blockIdx.x * 64;
  const int tr = threadIdx.x >> 4;
  const int tc = threadIdx.x & 15;
  #pragma unroll
  for (int i = 0; i < 4; i++) {
    int r = tr + i * 16;
    float4 v = *(const float4*)(W + (size_t)(r0 + r) * 512 + c0 + tc * 4);
    tle[r][tc * 4 + 0] = v.x;
    tle[r][tc * 4 + 1] = v.y;
    tle[r][tc * 4 + 2] = v.z;
    tle[r][tc * 4 + 3] = v.w;
  }
  __syncthreads();
  #pragma unroll
  for (int i = 0; i < 4; i++) {
    int c = tr + i * 16;
    int rr = tc * 4;
    uint2 p;
    p.x = packbf(tle[rr + 0][c], tle[rr + 1][c]);
    p.y = packbf(tle[rr + 2][c], tle[rr + 3][c]);
    *(uint2*)(WT + (size_t)(c0 + c) * 512 + r0 + rr) = p;
  }
}

// ---------------------------------------------------------------------------
// Barrier-free 64x128 GEMM K-loop: per-lane fragment loads straight from
// global (no LDS staging, no __syncthreads in the loop). A is fp32,
// converted to bf16 in registers; BT is bf16 row-major [n][k].
// Wave layout: wm=(w&1)*32 m-rows, wn=(w>>1)*64 n-cols, acc = 32x64.
// ---------------------------------------------------------------------------
__device__ __forceinline__ void gemm_loop_direct(const float* __restrict__ A,
                                                 const unsigned short* __restrict__ BT,
                                                 int m0, int n0, int w, int lane,
                                                 f32x16 (&acc)[2]) {
  const int l31 = lane & 31, lh = lane >> 5;
  const int wm = (w & 1) * 32, wn = (w >> 1) * 64;
  const float* Ar = A + (size_t)(m0 + wm + l31) * 512 + lh * 8;
  const unsigned short* B0 = BT + (size_t)(n0 + wn + l31) * 512 + lh * 8;
  const unsigned short* B1 = BT + (size_t)(n0 + wn + 32 + l31) * 512 + lh * 8;

  #pragma unroll 4
  for (int kt = 0; kt < 32; ++kt) {
    float4 a0 = *(const float4*)(Ar + kt * 16);
    float4 a1 = *(const float4*)(Ar + kt * 16 + 4);
    s16x8 b0 = *(const s16x8*)(B0 + kt * 16);
    s16x8 b1 = *(const s16x8*)(B1 + kt * 16);
    uint4 af4;
    af4.x = packbf(a0.x, a0.y); af4.y = packbf(a0.z, a0.w);
    af4.z = packbf(a1.x, a1.y); af4.w = packbf(a1.z, a1.w);
    s16x8 af = __builtin_bit_cast(s16x8, af4);
    acc[0] = MFMA32(af, b0, acc[0]);
    acc[1] = MFMA32(af, b1, acc[1]);
  }
}

// ---------------------------------------------------------------------------
// Fused Q/K/V projection. grid (4, 64, 3). LDS only in the epilogue.
// z=0: Q -> [bh][s][64] scaled QSCALE; z=1: K -> [bh][s][64]; z=2: V^T.
// ---------------------------------------------------------------------------
__global__ __launch_bounds__(256) void gemm_qkv(const float* __restrict__ frF,
                                                const float* __restrict__ dtF,
                                                const unsigned short* __restrict__ WqT,
                                                const unsigned short* __restrict__ WkT,
                                                const unsigned short* __restrict__ WvT,
                                                unsigned short* __restrict__ Qp,
                                                unsigned short* __restrict__ Kp,
                                                unsigned short* __restrict__ VTp) {
  __shared__ __align__(16) unsigned short smem[9216];  // epilogue only (18 KB)
  const int tid = threadIdx.x, lane = tid & 63, w = tid >> 6;
  const int l31 = lane & 31, lh = lane >> 5;
  const int m0 = blockIdx.y * 64, n0 = blockIdx.x * 128;
  const int z = blockIdx.z;
  const float* A = z == 0 ? frF : dtF;
  const unsigned short* BT = z == 0 ? WqT : (z == 1 ? WkT : WvT);
  unsigned short* OP = z == 0 ? Qp : (z == 1 ? Kp : VTp);
  const float scale = z == 0 ? QSCALE : 1.0f;

  f32x16 acc[2];
  #pragma unroll
  for (int j = 0; j < 2; j++)
    #pragma unroll
    for (int r = 0; r < 16; r++) acc[j][r] = 0.f;

  gemm_loop_direct(A, BT, m0, n0, w, lane, acc);

  const int wm = (w & 1) * 32, wn = (w >> 1) * 64;
  const int bb = m0 >> 11, s0 = m0 & 2047;
  if (z <= 1) {
    #pragma unroll
    for (int j = 0; j < 2; j++)
      #pragma unroll
      for (int r = 0; r < 16; r++) {
        int mm = wm + (r & 3) + 8 * (r >> 2) + 4 * lh;
        int nn = wn + j * 32 + l31;
        smem[mm * 136 + nn] = bfr(acc[j][r] * scale);
      }
    __syncthreads();
    #pragma unroll
    for (int it = 0; it < 4; ++it) {
      int c = tid + it * 256;
      int mm = c >> 4, seg = c & 15;
      uint4 vdat = *(const uint4*)(smem + mm * 136 + seg * 8);
      int n = n0 + seg * 8, h = n >> 6, d = n & 63;
      *(uint4*)(OP + ((size_t)((bb * NHEAD + h) * SEQ + s0 + mm)) * HD + d) = vdat;
    }
  } else {
    #pragma unroll
    for (int j = 0; j < 2; j++)
      #pragma unroll
      for (int r = 0; r < 16; r += 2) {
        int mm = wm + (r & 3) + 8 * (r >> 2) + 4 * lh;  // even
        int nn = wn + j * 32 + l31;
        *(unsigned int*)(smem + nn * 72 + mm) = packbf(acc[j][r], acc[j][r + 1]);
      }
    __syncthreads();
    #pragma unroll
    for (int it = 0; it < 4; ++it) {
      int c = tid + it * 256;
      int nn = c >> 3, seg = c & 7;
      uint4 vdat = *(const uint4*)(smem + nn * 72 + seg * 8);
      int n = n0 + nn, h = n >> 6, d = n & 63;
      *(uint4*)(OP + ((size_t)((bb * NHEAD + h) * HD + d)) * SEQ + s0 + seg * 8) = vdat;
    }
  }
}

// ---------------------------------------------------------------------------
// Final projection: out[4096,512] = bf16(ao) @ WoT^T + bias, fp32 out.
// Barrier-free loop (A already bf16 here), direct epilogue, no LDS.
// ---------------------------------------------------------------------------
__global__ __launch_bounds__(256) void gemm_out(const unsigned short* __restrict__ A,
                                                const unsigned short* __restrict__ BT,
                                                const float* __restrict__ bias,
                                                float* __restrict__ O) {
  const int tid = threadIdx.x, lane = tid & 63, w = tid >> 6;
  const int l31 = lane & 31, lh = lane >> 5;
  const int m0 = blockIdx.y * 64, n0 = blockIdx.x * 128;
  const int wm = (w & 1) * 32, wn = (w >> 1) * 64;

  const unsigned short* Ar = A + (size_t)(m0 + wm + l31) * 512 + lh * 8;
  const unsigned short* B0 = BT + (size_t)(n0 + wn + l31) * 512 + lh * 8;
  const unsigned short* B1 = BT + (size_t)(n0 + wn + 32 + l31) * 512 + lh * 8;

  f32x16 acc[2];
  #pragma unroll
  for (int j = 0; j < 2; j++)
    #pragma unroll
    for (int r = 0; r < 16; r++) acc[j][r] = 0.f;

  #pragma unroll 4
  for (int kt = 0; kt < 32; ++kt) {
    s16x8 af = *(const s16x8*)(Ar + kt * 16);
    s16x8 b0 = *(const s16x8*)(B0 + kt * 16);
    s16x8 b1 = *(const s16x8*)(B1 + kt * 16);
    acc[0] = MFMA32(af, b0, acc[0]);
    acc[1] = MFMA32(af, b1, acc[1]);
  }

  #pragma unroll
  for (int j = 0; j < 2; j++) {
    float bv = bias[n0 + wn + j * 32 + l31];
    #pragma unroll
    for (int r = 0; r < 16; r++) {
      int mm = wm + (r & 3) + 8 * (r >> 2) + 4 * lh;
      O[(size_t)(m0 + mm) * 512 + n0 + wn + j * 32 + l31] = acc[j][r] + bv;
    }
  }
}

// ---------------------------------------------------------------------------
// MFMA flash attention, renormalized clip, exp2 domain, no max pass.
// BARRIER-FREE K-loop: per-lane global fragment loads (no LDS staging).
// Block = 512 thr = 8 waves: wq = w&1 (32-q subtile), wk = w>>1 (512-key
// quarter). LDS (34 KB) used only for the cross-wk merges at the end.
// XCD-aware swizzle: 2 bh per XCD -> K/V working set 1 MB < 4 MB L2.
// ---------------------------------------------------------------------------
__global__ __launch_bounds__(512) void attn_mfma(const unsigned short* __restrict__ Q,
                                                 const unsigned short* __restrict__ K,
                                                 const unsigned short* __restrict__ VT,
                                                 unsigned short* __restrict__ O) {
  __shared__ float plane[4][2048];   // 32 KB merge scratch
  __shared__ float larr[4][2][32];
  __shared__ float warr[4][2][32];

  const int tid = threadIdx.x;
  const int lane = tid & 63;
  const int w = tid >> 6;
  const int wq = w & 1, wk = w >> 1;
  const int l31 = lane & 31, lh = lane >> 5;

  // XCD swizzle: dispatch round-robins XCDs on blockIdx; keep one bh-pair/XCD
  const int bid = blockIdx.x;
  const int g = bid & 7, j = bid >> 3;
  const int bh = g * 2 + (j >> 5);
  const int qt = j & 31;

  const unsigned short* Qh = Q + (size_t)bh * SEQ * HD;
  const unsigned short* Kh = K + (size_t)bh * SEQ * HD;
  const unsigned short* VTh = VT + (size_t)bh * HD * SEQ;

  // Q B-fragments: this wave's 32 q rows (pre-scaled by 0.125*log2e)
  const int qrow = qt * 64 + wq * 32 + l31;
  s16x8 qf[4];
  #pragma unroll
  for (int t = 0; t < 4; t++)
    qf[t] = *(const s16x8*)(Qh + (size_t)qrow * HD + 16 * t + 8 * lh);

  const int kbase = wk * 512;
  const unsigned short* Kr = Kh + (size_t)(kbase + l31) * HD + lh * 8;

  // ---------------- sweep 1: per-q l = sum(exp2(s)), no barriers ----------
  float l = 0.f;
  #pragma unroll 2
  for (int c = 0; c < 16; ++c) {
    const unsigned short* kp = Kr + (size_t)c * 32 * HD;
    s16x8 k0 = *(const s16x8*)(kp + 0);
    s16x8 k1 = *(const s16x8*)(kp + 16);
    s16x8 k2 = *(const s16x8*)(kp + 32);
    s16x8 k3 = *(const s16x8*)(kp + 48);
    f32x16 sc;
    #pragma unroll
    for (int r = 0; r < 16; r++) sc[r] = 0.f;
    sc = MFMA32(k0, qf[0], sc);
    sc = MFMA32(k1, qf[1], sc);
    sc = MFMA32(k2, qf[2], sc);
    sc = MFMA32(k3, qf[3], sc);
    float s0 = 0.f, s1 = 0.f, s2 = 0.f, s3 = 0.f;
    #pragma unroll
    for (int r = 0; r < 4; r++) {
      s0 += EXP2(sc[r]);
      s1 += EXP2(sc[4 + r]);
      s2 += EXP2(sc[8 + r]);
      s3 += EXP2(sc[12 + r]);
    }
    l += (s0 + s1) + (s2 + s3);
  }
  l += __shfl_xor(l, 32);
  if (lh == 0) larr[wk][wq][l31] = l;
  __syncthreads();  // larr visible block-wide

  const float tl = ATT_T * (larr[0][wq][l31] + larr[1][wq][l31] +
                            larr[2][wq][l31] + larr[3][wq][l31]);

  // ---------------- sweep 2: clip + PV, no barriers ----------------
  f32x16 acc[2];
  #pragma unroll
  for (int jj = 0; jj < 2; jj++)
    #pragma unroll
    for (int r = 0; r < 16; r++) acc[jj][r] = 0.f;
  float wacc = 0.f;

  const unsigned short* V0 = VTh + (size_t)(l31) * SEQ + kbase + lh * 8;
  const unsigned short* V1 = VTh + (size_t)(32 + l31) * SEQ + kbase + lh * 8;

  #pragma unroll 2
  for (int c = 0; c < 16; ++c) {
    const unsigned short* kp = Kr + (size_t)c * 32 * HD;
    s16x8 k0 = *(const s16x8*)(kp + 0);
    s16x8 k1 = *(const s16x8*)(kp + 16);
    s16x8 k2 = *(const s16x8*)(kp + 32);
    s16x8 k3 = *(const s16x8*)(kp + 48);
    s16x8 va0 = *(const s16x8*)(V0 + c * 32);        // d 0..31,  keys +0..15
    s16x8 va1 = *(const s16x8*)(V0 + c * 32 + 16);   // d 0..31,  keys +16..31
    s16x8 vb0 = *(const s16x8*)(V1 + c * 32);        // d 32..63
    s16x8 vb1 = *(const s16x8*)(V1 + c * 32 + 16);
    f32x16 sc;
    #pragma unroll
    for (int r = 0; r < 16; r++) sc[r] = 0.f;
    sc = MFMA32(k0, qf[0], sc);
    sc = MFMA32(k1, qf[1], sc);
    sc = MFMA32(k2, qf[2], sc);
    sc = MFMA32(k3, qf[3], sc);

    uint2 quads[4];
    #pragma unroll
    for (int gq = 0; gq < 4; gq++) {
      float u0 = fmaxf(EXP2(sc[4 * gq + 0]) - tl, 0.f);
      float u1 = fmaxf(EXP2(sc[4 * gq + 1]) - tl, 0.f);
      float u2 = fmaxf(EXP2(sc[4 * gq + 2]) - tl, 0.f);
      float u3 = fmaxf(EXP2(sc[4 * gq + 3]) - tl, 0.f);
      wacc += (u0 + u1) + (u2 + u3);
      quads[gq].x = packbf(u0, u1);
      quads[gq].y = packbf(u2, u3);
    }
    s16x8 pf[2];
    #pragma unroll
    for (int tp = 0; tp < 2; tp++) {
      uint2 ea, eb;
      ea.x = (unsigned)__shfl_xor((int)quads[2 * tp].x, 32);
      ea.y = (unsigned)__shfl_xor((int)quads[2 * tp].y, 32);
      eb.x = (unsigned)__shfl_xor((int)quads[2 * tp + 1].x, 32);
      eb.y = (unsigned)__shfl_xor((int)quads[2 * tp + 1].y, 32);
      uint4 fr;
      if (lh == 0) { fr.x = quads[2 * tp].x; fr.y = quads[2 * tp].y; fr.z = ea.x; fr.w = ea.y; }
      else         { fr.x = eb.x; fr.y = eb.y; fr.z = quads[2 * tp + 1].x; fr.w = quads[2 * tp + 1].y; }
      pf[tp] = __builtin_bit_cast(s16x8, fr);
    }
    acc[0] = MFMA32(pf[0], va0, acc[0]);
    acc[0] = MFMA32(pf[1], va1, acc[0]);
    acc[1] = MFMA32(pf[0], vb0, acc[1]);
    acc[1] = MFMA32(pf[1], vb1, acc[1]);
  }

  // ---------------- cross-wk merge + output ----------------
  wacc += __shfl_xor(wacc, 32);
  if (lh == 0) warr[wk][wq][l31] = wacc;

  if (wk >= 2) {
    const int p = wq * 2 + (wk - 2);
    #pragma unroll
    for (int jj = 0; jj < 2; jj++)
      #pragma unroll
      for (int r = 0; r < 16; r++) {
        int ql = (r & 3) + 8 * (r >> 2) + 4 * lh;
        plane[p][ql * 64 + jj * 32 + l31] = acc[jj][r];
      }
  }
  __syncthreads();
  if (wk < 2) {
    const int p = wq * 2 + wk;
    #pragma unroll
    for (int jj = 0; jj < 2; jj++)
      #pragma unroll
      for (int r = 0; r < 16; r++) {
        int ql = (r & 3) + 8 * (r >> 2) + 4 * lh;
        acc[jj][r] += plane[p][ql * 64 + jj * 32 + l31];
      }
  }
  __syncthreads();
  if (wk == 1) {
    #pragma unroll
    for (int jj = 0; jj < 2; jj++)
      #pragma unroll
      for (int r = 0; r < 16; r++) {
        int ql = (r & 3) + 8 * (r >> 2) + 4 * lh;
        plane[wq][ql * 64 + jj * 32 + l31] = acc[jj][r];
      }
  }
  __syncthreads();
  unsigned short* otile = (unsigned short*)&plane[2][0];  // 8 KB, disjoint from planes 0/1
  if (wk == 0) {
    #pragma unroll
    for (int jj = 0; jj < 2; jj++)
      #pragma unroll
      for (int r = 0; r < 16; r++) {
        int ql = (r & 3) + 8 * (r >> 2) + 4 * lh;
        float wt = warr[0][wq][ql] + warr[1][wq][ql] + warr[2][wq][ql] + warr[3][wq][ql];
        float v = (acc[jj][r] + plane[wq][ql * 64 + jj * 32 + l31]) / wt;
        otile[(wq * 32 + ql) * 64 + jj * 32 + l31] = bfr(v);
      }
  }
  __syncthreads();
  const int b = bh >> 3, h = bh & 7;
  {
    int mm = tid >> 3, seg = tid & 7;
    uint4 vdat = *(const uint4*)(otile + mm * 64 + seg * 8);
    *(uint4*)(O + ((size_t)(b * SEQ + qt * 64 + mm)) * 512 + h * HD + seg * 8) = vdat;
  }
}

// ---------------------------------------------------------------------------
extern "C" void kernel_launch(void* const* d_in, const int* in_sizes, int n_in,
                              void* d_out, int out_size, void* d_ws, size_t ws_size,
                              hipStream_t stream) {
  const float* fr = (const float*)d_in[0];
  const float* dt = (const float*)d_in[1];
  const float* Wq = (const float*)d_in[2];
  const float* Wk = (const float*)d_in[3];
  const float* Wv = (const float*)d_in[4];
  const float* Wo = (const float*)d_in[5];
  const float* bo = (const float*)d_in[6];
  float* out = (float*)d_out;

  const size_t planeE = (size_t)BB * SEQ * 512;  // 2,097,152 elements
  const size_t wE = 512 * 512;
  unsigned short* p = (unsigned short*)d_ws;
  unsigned short* WqT = p; p += wE;
  unsigned short* WkT = p; p += wE;
  unsigned short* WvT = p; p += wE;
  unsigned short* WoT = p; p += wE;
  unsigned short* Qp  = p; p += planeE;
  unsigned short* Kp  = p; p += planeE;
  unsigned short* VTp = p; p += planeE;
  unsigned short* aoB = p; p += planeE;

  convT<<<dim3(8, 8, 4), 256, 0, stream>>>(Wq, Wk, Wv, Wo, WqT, WkT, WvT, WoT);

  gemm_qkv<<<dim3(4, 64, 3), 256, 0, stream>>>(fr, dt, WqT, WkT, WvT, Qp, Kp, VTp);

  attn_mfma<<<BB * NHEAD * 32, 512, 0, stream>>>(Qp, Kp, VTp, aoB);

  gemm_out<<<dim3(4, 64), 256, 0, stream>>>(aoB, WoT, bo, out);
}

// Round 8
// 172.460 us; speedup vs baseline: 1.3819x; 1.3819x over previous
//
#include <hip/hip_runtime.h>
#include <hip/hip_bf16.h>

#define BB 2
#define SEQ 2048
#define NHEAD 8
#define HD 64
#define ATT_T 1e-4f
#define QSCALE 0.18033688011112042f  // 0.125 * log2(e): scores in log2 domain

typedef short s16x8 __attribute__((ext_vector_type(8)));
typedef float f32x16 __attribute__((ext_vector_type(16)));

#define MFMA32(a, b, c) __builtin_amdgcn_mfma_f32_32x32x16_bf16((a), (b), (c), 0, 0, 0)
#define EXP2(x) __builtin_amdgcn_exp2f(x)

__device__ __forceinline__ unsigned short bfr(float x) {
  __hip_bfloat16 h = __float2bfloat16(x);
  return __builtin_bit_cast(unsigned short, h);
}
__device__ __forceinline__ unsigned int packbf(float a, float b) {
  return (unsigned int)bfr(a) | ((unsigned int)bfr(b) << 16);
}
__device__ __forceinline__ void async16(const void* g, void* l) {
  __builtin_amdgcn_global_load_lds(
      (const __attribute__((address_space(1))) unsigned int*)g,
      (__attribute__((address_space(3))) unsigned int*)l, 16, 0, 0);
}

// ---------------------------------------------------------------------------
// fp32 -> bf16 convert, fr and dt in one launch (grid.y selects)
// ---------------------------------------------------------------------------
__global__ __launch_bounds__(256) void conv_bf16(const float* __restrict__ x0,
                                                 const float* __restrict__ x1,
                                                 unsigned short* __restrict__ y0,
                                                 unsigned short* __restrict__ y1) {
  const float* x = blockIdx.y ? x1 : x0;
  unsigned short* y = blockIdx.y ? y1 : y0;
  size_t i = ((size_t)blockIdx.x * 256 + threadIdx.x) * 4;
  float4 v = *(const float4*)(x + i);
  uint2 p;
  p.x = packbf(v.x, v.y);
  p.y = packbf(v.z, v.w);
  *(uint2*)(y + i) = p;
}

// ---------------------------------------------------------------------------
// Transpose-convert: WT[n][k] = bf16(W[k][n]), 512x512, 4 matrices batched.
// ---------------------------------------------------------------------------
__global__ __launch_bounds__(256) void convT(const float* __restrict__ w0,
                                             const float* __restrict__ w1,
                                             const float* __restrict__ w2,
                                             const float* __restrict__ w3,
                                             unsigned short* __restrict__ o0,
                                             unsigned short* __restrict__ o1,
                                             unsigned short* __restrict__ o2,
                                             unsigned short* __restrict__ o3) {
  __shared__ float tle[64][65];
  const float* W = blockIdx.z == 0 ? w0 : blockIdx.z == 1 ? w1 : blockIdx.z == 2 ? w2 : w3;
  unsigned short* WT = blockIdx.z == 0 ? o0 : blockIdx.z == 1 ? o1 : blockIdx.z == 2 ? o2 : o3;
  const int r0 = blockIdx.y * 64, c0 = blockIdx.x * 64;
  const int tr = threadIdx.x >> 4;
  const int tc = threadIdx.x & 15;
  #pragma unroll
  for (int i = 0; i < 4; i++) {
    int r = tr + i * 16;
    float4 v = *(const float4*)(W + (size_t)(r0 + r) * 512 + c0 + tc * 4);
    tle[r][tc * 4 + 0] = v.x;
    tle[r][tc * 4 + 1] = v.y;
    tle[r][tc * 4 + 2] = v.z;
    tle[r][tc * 4 + 3] = v.w;
  }
  __syncthreads();
  #pragma unroll
  for (int i = 0; i < 4; i++) {
    int c = tr + i * 16;
    int rr = tc * 4;
    uint2 p;
    p.x = packbf(tle[rr + 0][c], tle[rr + 1][c]);
    p.y = packbf(tle[rr + 2][c], tle[rr + 3][c]);
    *(uint2*)(WT + (size_t)(c0 + c) * 512 + r0 + rr) = p;
  }
}

// ---------------------------------------------------------------------------
// 64x128-tile bf16 MFMA GEMM core, BK=64 (8 barrier windows), 256 thr =
// 4 waves (2 m-subtiles x 2 n-subtiles). Frag-order staging via
// global_load_lds(16B): conflict-free ds_read_b128. 48 KB LDS, dbuf.
// ---------------------------------------------------------------------------
__device__ __forceinline__ void gemm_core_bk64(const unsigned short* __restrict__ A,
                                               const unsigned short* __restrict__ BT,
                                               unsigned short* smem, int m0, int n0,
                                               int w, int lane, f32x16 (&acc)[2]) {
  unsigned short* Asm = smem;            // 2 buf x 4096 ushorts
  unsigned short* Bsm = smem + 8192;     // 2 buf x 8192 ushorts
  const int l31 = lane & 31, lh = lane >> 5;

  auto stage = [&](int kt, int buf) {
    const int k0 = kt * 64;
    #pragma unroll
    for (int i = 0; i < 2; i++) {
      int r = w * 2 + i, g = r >> 2, ks = r & 3;
      async16(A + (size_t)(m0 + g * 32 + l31) * 512 + k0 + ks * 16 + lh * 8,
              Asm + buf * 4096 + r * 512);
    }
    #pragma unroll
    for (int i = 0; i < 4; i++) {
      int r = w * 4 + i, gn = r >> 2, ks = r & 3;
      async16(BT + (size_t)(n0 + gn * 32 + l31) * 512 + k0 + ks * 16 + lh * 8,
              Bsm + buf * 8192 + r * 512);
    }
  };

  stage(0, 0);
  for (int kt = 0; kt < 8; ++kt) {
    __syncthreads();
    if (kt + 1 < 8) stage(kt + 1, (kt + 1) & 1);
    const int buf = kt & 1;
    const unsigned short* as = Asm + buf * 4096 + (w & 1) * 2048;
    const unsigned short* bs = Bsm + buf * 8192 + (w >> 1) * 4096;
    #pragma unroll
    for (int ks = 0; ks < 4; ++ks) {
      s16x8 af = *(const s16x8*)(as + ks * 512 + lane * 8);
      s16x8 b0 = *(const s16x8*)(bs + ks * 512 + lane * 8);
      s16x8 b1 = *(const s16x8*)(bs + 2048 + ks * 512 + lane * 8);
      acc[0] = MFMA32(af, b0, acc[0]);
      acc[1] = MFMA32(af, b1, acc[1]);
    }
  }
}

// ---------------------------------------------------------------------------
// Fused Q/K/V projection GEMM. grid (4, 64, 3): z picks matrix & epilogue.
// z=0: Q -> [bh][s][64] scaled QSCALE; z=1: K -> [bh][s][64]; z=2: V^T.
// ---------------------------------------------------------------------------
__global__ __launch_bounds__(256) void gemm_qkv(const unsigned short* __restrict__ frB,
                                                const unsigned short* __restrict__ dtB,
                                                const unsigned short* __restrict__ WqT,
                                                const unsigned short* __restrict__ WkT,
                                                const unsigned short* __restrict__ WvT,
                                                unsigned short* __restrict__ Qp,
                                                unsigned short* __restrict__ Kp,
                                                unsigned short* __restrict__ VTp) {
  __shared__ __align__(16) unsigned short smem[24576];  // 48 KB staging / epilogue reuse
  const int tid = threadIdx.x, lane = tid & 63, w = tid >> 6;
  const int l31 = lane & 31, lh = lane >> 5;
  const int m0 = blockIdx.y * 64, n0 = blockIdx.x * 128;
  const int z = blockIdx.z;
  const unsigned short* A = z == 0 ? frB : dtB;
  const unsigned short* BT = z == 0 ? WqT : (z == 1 ? WkT : WvT);
  unsigned short* OP = z == 0 ? Qp : (z == 1 ? Kp : VTp);
  const float scale = z == 0 ? QSCALE : 1.0f;

  f32x16 acc[2];
  #pragma unroll
  for (int j = 0; j < 2; j++)
    #pragma unroll
    for (int r = 0; r < 16; r++) acc[j][r] = 0.f;

  gemm_core_bk64(A, BT, smem, m0, n0, w, lane, acc);

  const int wm = (w & 1) * 32, wn = (w >> 1) * 64;
  const int bb = m0 >> 11, s0 = m0 & 2047;
  __syncthreads();
  if (z <= 1) {
    #pragma unroll
    for (int j = 0; j < 2; j++)
      #pragma unroll
      for (int r = 0; r < 16; r++) {
        int mm = wm + (r & 3) + 8 * (r >> 2) + 4 * lh;
        int nn = wn + j * 32 + l31;
        smem[mm * 136 + nn] = bfr(acc[j][r] * scale);
      }
    __syncthreads();
    #pragma unroll
    for (int it = 0; it < 4; ++it) {
      int c = tid + it * 256;
      int mm = c >> 4, seg = c & 15;
      uint4 vdat = *(const uint4*)(smem + mm * 136 + seg * 8);
      int n = n0 + seg * 8, h = n >> 6, d = n & 63;
      *(uint4*)(OP + ((size_t)((bb * NHEAD + h) * SEQ + s0 + mm)) * HD + d) = vdat;
    }
  } else {
    #pragma unroll
    for (int j = 0; j < 2; j++)
      #pragma unroll
      for (int r = 0; r < 16; r += 2) {
        int mm = wm + (r & 3) + 8 * (r >> 2) + 4 * lh;  // even
        int nn = wn + j * 32 + l31;
        *(unsigned int*)(smem + nn * 72 + mm) = packbf(acc[j][r], acc[j][r + 1]);
      }
    __syncthreads();
    #pragma unroll
    for (int it = 0; it < 4; ++it) {
      int c = tid + it * 256;
      int nn = c >> 3, seg = c & 7;
      uint4 vdat = *(const uint4*)(smem + nn * 72 + seg * 8);
      int n = n0 + nn, h = n >> 6, d = n & 63;
      *(uint4*)(OP + ((size_t)((bb * NHEAD + h) * HD + d)) * SEQ + s0 + seg * 8) = vdat;
    }
  }
}

// ---------------------------------------------------------------------------
// Final projection: out[4096,512] = aoB @ WoT^T + bias, fp32 out.
// ---------------------------------------------------------------------------
__global__ __launch_bounds__(256) void gemm_out(const unsigned short* __restrict__ A,
                                                const unsigned short* __restrict__ BT,
                                                const float* __restrict__ bias,
                                                float* __restrict__ O) {
  __shared__ __align__(16) unsigned short smem[24576];
  const int tid = threadIdx.x, lane = tid & 63, w = tid >> 6;
  const int l31 = lane & 31, lh = lane >> 5;
  const int m0 = blockIdx.y * 64, n0 = blockIdx.x * 128;

  f32x16 acc[2];
  #pragma unroll
  for (int j = 0; j < 2; j++)
    #pragma unroll
    for (int r = 0; r < 16; r++) acc[j][r] = 0.f;

  gemm_core_bk64(A, BT, smem, m0, n0, w, lane, acc);

  const int wm = (w & 1) * 32, wn = (w >> 1) * 64;
  #pragma unroll
  for (int j = 0; j < 2; j++) {
    float bv = bias[n0 + wn + j * 32 + l31];
    #pragma unroll
    for (int r = 0; r < 16; r++) {
      int mm = wm + (r & 3) + 8 * (r >> 2) + 4 * lh;
      O[(size_t)(m0 + mm) * 512 + n0 + wn + j * 32 + l31] = acc[j][r] + bv;
    }
  }
}

// ---------------------------------------------------------------------------
// MFMA flash attention (R6 structure), renormalized clip, exp2 domain,
// no max pass. Block = 512 thr = 8 waves: wq = w&1, wk = w>>1 (512-key
// quarter). LDS-staged K/V via global_load_lds, dbuf, 32-key chunks.
// XCD-aware swizzle: 2 bh pinned per XCD -> K/V L2-resident (~1 MB/XCD),
// so the per-window vmcnt drain is L2-latency not HBM-latency.
// ---------------------------------------------------------------------------
__global__ __launch_bounds__(512, 4) void attn_mfma(const unsigned short* __restrict__ Q,
                                                    const unsigned short* __restrict__ K,
                                                    const unsigned short* __restrict__ VT,
                                                    unsigned short* __restrict__ O) {
  __shared__ __align__(16) unsigned short kls[4][2][2048];  // 32 KB
  __shared__ __align__(16) unsigned short vls[4][2][2048];  // 32 KB
  __shared__ float larr[4][2][32];
  __shared__ float warr[4][2][32];

  const int tid = threadIdx.x;
  const int lane = tid & 63;
  const int w = tid >> 6;
  const int wq = w & 1, wk = w >> 1;
  const int l31 = lane & 31, lh = lane >> 5;

  // XCD swizzle: dispatch round-robins XCDs on blockIdx; pin 2 bh per XCD
  const int bid = blockIdx.x;
  const int g = bid & 7, j = bid >> 3;
  const int bh = g * 2 + (j >> 5);
  const int qt = j & 31;

  const unsigned short* Qh = Q + (size_t)bh * SEQ * HD;
  const unsigned short* Kh = K + (size_t)bh * SEQ * HD;
  const unsigned short* VTh = VT + (size_t)bh * HD * SEQ;

  // Q B-fragments: this wave's 32 q rows (pre-scaled by 0.125*log2e)
  const int qrow = qt * 64 + wq * 32 + l31;
  s16x8 qf[4];
  #pragma unroll
  for (int t = 0; t < 4; t++)
    qf[t] = *(const s16x8*)(Qh + (size_t)qrow * HD + 16 * t + 8 * lh);

  const int kbase = wk * 512;

  // ---------------- sweep 1: per-q l = sum(exp2(s)) ----------------
  float l = 0.f;
  #pragma unroll
  for (int i = 0; i < 2; i++) {
    int tt = wq * 2 + i;
    async16(Kh + (size_t)(kbase + l31) * HD + tt * 16 + lh * 8, &kls[wk][0][tt * 512]);
  }
  for (int c = 0; c < 16; ++c) {
    __syncthreads();
    const int buf = c & 1;
    if (c + 1 < 16) {
      int key0 = kbase + (c + 1) * 32;
      #pragma unroll
      for (int i = 0; i < 2; i++) {
        int tt = wq * 2 + i;
        async16(Kh + (size_t)(key0 + l31) * HD + tt * 16 + lh * 8,
                &kls[wk][buf ^ 1][tt * 512]);
      }
    }
    f32x16 sc;
    #pragma unroll
    for (int r = 0; r < 16; r++) sc[r] = 0.f;
    #pragma unroll
    for (int tt = 0; tt < 4; tt++) {
      s16x8 kf = *(const s16x8*)&kls[wk][buf][tt * 512 + lane * 8];
      sc = MFMA32(kf, qf[tt], sc);
    }
    float s0 = 0.f, s1 = 0.f, s2 = 0.f, s3 = 0.f;
    #pragma unroll
    for (int r = 0; r < 4; r++) {
      s0 += EXP2(sc[r]);
      s1 += EXP2(sc[4 + r]);
      s2 += EXP2(sc[8 + r]);
      s3 += EXP2(sc[12 + r]);
    }
    l += (s0 + s1) + (s2 + s3);
  }
  l += __shfl_xor(l, 32);
  if (lh == 0) larr[wk][wq][l31] = l;

  // ---------------- sweep 2: clip + PV ----------------
  f32x16 acc[2];
  #pragma unroll
  for (int jj = 0; jj < 2; jj++)
    #pragma unroll
    for (int r = 0; r < 16; r++) acc[jj][r] = 0.f;
  float wacc = 0.f;
  float tl = 0.f;

  #pragma unroll
  for (int i = 0; i < 2; i++) {
    int tt = wq * 2 + i;
    async16(Kh + (size_t)(kbase + l31) * HD + tt * 16 + lh * 8, &kls[wk][0][tt * 512]);
    async16(VTh + (size_t)(wq * 32 + l31) * SEQ + kbase + i * 16 + lh * 8,
            &vls[wk][0][(wq * 2 + i) * 512]);
  }
  for (int c = 0; c < 16; ++c) {
    __syncthreads();
    if (c == 0) {  // cross-wk l merge (larr visible after barrier)
      tl = ATT_T * (larr[0][wq][l31] + larr[1][wq][l31] +
                    larr[2][wq][l31] + larr[3][wq][l31]);
    }
    const int buf = c & 1;
    if (c + 1 < 16) {
      int key0 = kbase + (c + 1) * 32;
      #pragma unroll
      for (int i = 0; i < 2; i++) {
        int tt = wq * 2 + i;
        async16(Kh + (size_t)(key0 + l31) * HD + tt * 16 + lh * 8,
                &kls[wk][buf ^ 1][tt * 512]);
        async16(VTh + (size_t)(wq * 32 + l31) * SEQ + key0 + i * 16 + lh * 8,
                &vls[wk][buf ^ 1][(wq * 2 + i) * 512]);
      }
    }
    f32x16 sc;
    #pragma unroll
    for (int r = 0; r < 16; r++) sc[r] = 0.f;
    #pragma unroll
    for (int tt = 0; tt < 4; tt++) {
      s16x8 kf = *(const s16x8*)&kls[wk][buf][tt * 512 + lane * 8];
      sc = MFMA32(kf, qf[tt], sc);
    }
    uint2 quads[4];
    #pragma unroll
    for (int gq = 0; gq < 4; gq++) {
      float u0 = fmaxf(EXP2(sc[4 * gq + 0]) - tl, 0.f);
      float u1 = fmaxf(EXP2(sc[4 * gq + 1]) - tl, 0.f);
      float u2 = fmaxf(EXP2(sc[4 * gq + 2]) - tl, 0.f);
      float u3 = fmaxf(EXP2(sc[4 * gq + 3]) - tl, 0.f);
      wacc += (u0 + u1) + (u2 + u3);
      quads[gq].x = packbf(u0, u1);
      quads[gq].y = packbf(u2, u3);
    }
    s16x8 pf[2];
    #pragma unroll
    for (int tp = 0; tp < 2; tp++) {
      uint2 ea, eb;
      ea.x = (unsigned)__shfl_xor((int)quads[2 * tp].x, 32);
      ea.y = (unsigned)__shfl_xor((int)quads[2 * tp].y, 32);
      eb.x = (unsigned)__shfl_xor((int)quads[2 * tp + 1].x, 32);
      eb.y = (unsigned)__shfl_xor((int)quads[2 * tp + 1].y, 32);
      uint4 fr;
      if (lh == 0) { fr.x = quads[2 * tp].x; fr.y = quads[2 * tp].y; fr.z = ea.x; fr.w = ea.y; }
      else         { fr.x = eb.x; fr.y = eb.y; fr.z = quads[2 * tp + 1].x; fr.w = quads[2 * tp + 1].y; }
      pf[tp] = __builtin_bit_cast(s16x8, fr);
    }
    #pragma unroll
    for (int kc = 0; kc < 2; kc++) {
      s16x8 v0 = *(const s16x8*)&vls[wk][buf][(0 * 2 + kc) * 512 + lane * 8];
      s16x8 v1 = *(const s16x8*)&vls[wk][buf][(1 * 2 + kc) * 512 + lane * 8];
      acc[0] = MFMA32(pf[kc], v0, acc[0]);
      acc[1] = MFMA32(pf[kc], v1, acc[1]);
    }
  }

  // ---------------- cross-wk merge + output ----------------
  __syncthreads();
  wacc += __shfl_xor(wacc, 32);
  if (lh == 0) warr[wk][wq][l31] = wacc;

  float* plane = (float*)&kls[0][0][0];       // 4 planes x 2048 fp32 (32 KB)
  unsigned short* otile = &vls[0][0][0];      // 64x64 bf16 (8 KB)

  if (wk >= 2) {
    const int p = wq * 2 + (wk - 2);
    #pragma unroll
    for (int jj = 0; jj < 2; jj++)
      #pragma unroll
      for (int r = 0; r < 16; r++) {
        int ql = (r & 3) + 8 * (r >> 2) + 4 * lh;
        plane[p * 2048 + ql * 64 + jj * 32 + l31] = acc[jj][r];
      }
  }
  __syncthreads();
  if (wk < 2) {
    const int p = wq * 2 + wk;
    #pragma unroll
    for (int jj = 0; jj < 2; jj++)
      #pragma unroll
      for (int r = 0; r < 16; r++) {
        int ql = (r & 3) + 8 * (r >> 2) + 4 * lh;
        acc[jj][r] += plane[p * 2048 + ql * 64 + jj * 32 + l31];
      }
  }
  __syncthreads();
  if (wk == 1) {
    #pragma unroll
    for (int jj = 0; jj < 2; jj++)
      #pragma unroll
      for (int r = 0; r < 16; r++) {
        int ql = (r & 3) + 8 * (r >> 2) + 4 * lh;
        plane[wq * 2048 + ql * 64 + jj * 32 + l31] = acc[jj][r];
      }
  }
  __syncthreads();
  if (wk == 0) {
    #pragma unroll
    for (int jj = 0; jj < 2; jj++)
      #pragma unroll
      for (int r = 0; r < 16; r++) {
        int ql = (r & 3) + 8 * (r >> 2) + 4 * lh;
        float wt = warr[0][wq][ql] + warr[1][wq][ql] + warr[2][wq][ql] + warr[3][wq][ql];
        float v = (acc[jj][r] + plane[wq * 2048 + ql * 64 + jj * 32 + l31]) / wt;
        otile[(wq * 32 + ql) * 64 + jj * 32 + l31] = bfr(v);
      }
  }
  __syncthreads();
  const int b = bh >> 3, h = bh & 7;
  {
    int mm = tid >> 3, seg = tid & 7;
    uint4 vdat = *(const uint4*)(otile + mm * 64 + seg * 8);
    *(uint4*)(O + ((size_t)(b * SEQ + qt * 64 + mm)) * 512 + h * HD + seg * 8) = vdat;
  }
}

// ---------------------------------------------------------------------------
extern "C" void kernel_launch(void* const* d_in, const int* in_sizes, int n_in,
                              void* d_out, int out_size, void* d_ws, size_t ws_size,
                              hipStream_t stream) {
  const float* fr = (const float*)d_in[0];
  const float* dt = (const float*)d_in[1];
  const float* Wq = (const float*)d_in[2];
  const float* Wk = (const float*)d_in[3];
  const float* Wv = (const float*)d_in[4];
  const float* Wo = (const float*)d_in[5];
  const float* bo = (const float*)d_in[6];
  float* out = (float*)d_out;

  const size_t planeE = (size_t)BB * SEQ * 512;  // 2,097,152 elements
  const size_t wE = 512 * 512;
  unsigned short* p = (unsigned short*)d_ws;
  unsigned short* frB = p; p += planeE;
  unsigned short* dtB = p; p += planeE;
  unsigned short* WqT = p; p += wE;
  unsigned short* WkT = p; p += wE;
  unsigned short* WvT = p; p += wE;
  unsigned short* WoT = p; p += wE;
  unsigned short* Qp  = p; p += planeE;
  unsigned short* Kp  = p; p += planeE;
  unsigned short* VTp = p; p += planeE;
  unsigned short* aoB = p; p += planeE;

  conv_bf16<<<dim3(2048, 2), 256, 0, stream>>>(fr, dt, frB, dtB);
  convT<<<dim3(8, 8, 4), 256, 0, stream>>>(Wq, Wk, Wv, Wo, WqT, WkT, WvT, WoT);

  gemm_qkv<<<dim3(4, 64, 3), 256, 0, stream>>>(frB, dtB, WqT, WkT, WvT, Qp, Kp, VTp);

  attn_mfma<<<BB * NHEAD * 32, 512, 0, stream>>>(Qp, Kp, VTp, aoB);

  gemm_out<<<dim3(4, 64), 256, 0, stream>>>(aoB, WoT, bo, out);
}

// Round 10
// 165.770 us; speedup vs baseline: 1.4376x; 1.0404x over previous
//
#include <hip/hip_runtime.h>
#include <hip/hip_bf16.h>

#define BB 2
#define SEQ 2048
#define NHEAD 8
#define HD 64
#define ATT_T 1e-4f
#define QSCALE 0.18033688011112042f  // 0.125 * log2(e): scores in log2 domain

typedef short s16x8 __attribute__((ext_vector_type(8)));
typedef float f32x16 __attribute__((ext_vector_type(16)));

#define MFMA32(a, b, c) __builtin_amdgcn_mfma_f32_32x32x16_bf16((a), (b), (c), 0, 0, 0)
#define EXP2(x) __builtin_amdgcn_exp2f(x)
#define SB0() __builtin_amdgcn_sched_barrier(0)
// s_waitcnt imm: vmcnt[3:0]=bits3:0, expcnt=bits6:4, lgkmcnt=bits11:8, vmcnt[5:4]=bits15:14
#define WAITVM0() __builtin_amdgcn_s_waitcnt(0x0F70)
#define WAITVM4() __builtin_amdgcn_s_waitcnt(0x0F74)
#define WAITVM8() __builtin_amdgcn_s_waitcnt(0x0F78)

__device__ __forceinline__ unsigned short bfr(float x) {
  __hip_bfloat16 h = __float2bfloat16(x);
  return __builtin_bit_cast(unsigned short, h);
}
__device__ __forceinline__ unsigned int packbf(float a, float b) {
  return (unsigned int)bfr(a) | ((unsigned int)bfr(b) << 16);
}
__device__ __forceinline__ void async16(const void* g, void* l) {
  __builtin_amdgcn_global_load_lds(
      (const __attribute__((address_space(1))) unsigned int*)g,
      (__attribute__((address_space(3))) unsigned int*)l, 16, 0, 0);
}

// ---------------------------------------------------------------------------
// prep: fp32->bf16 convert of fr/dt (blocks 0..4095) + weight transpose-
// convert WT[n][k]=bf16(W[k][n]) for 4 matrices (blocks 4096..4351).
// ---------------------------------------------------------------------------
__global__ __launch_bounds__(256) void prep(const float* __restrict__ fr,
                                            const float* __restrict__ dt,
                                            const float* __restrict__ w0,
                                            const float* __restrict__ w1,
                                            const float* __restrict__ w2,
                                            const float* __restrict__ w3,
                                            unsigned short* __restrict__ frB,
                                            unsigned short* __restrict__ dtB,
                                            unsigned short* __restrict__ o0,
                                            unsigned short* __restrict__ o1,
                                            unsigned short* __restrict__ o2,
                                            unsigned short* __restrict__ o3) {
  __shared__ float tle[64][65];
  const int bid = blockIdx.x;
  if (bid < 4096) {
    const float* x = bid < 2048 ? fr : dt;
    unsigned short* y = bid < 2048 ? frB : dtB;
    size_t i = ((size_t)(bid & 2047) * 256 + threadIdx.x) * 4;
    float4 v = *(const float4*)(x + i);
    uint2 p;
    p.x = packbf(v.x, v.y);
    p.y = packbf(v.z, v.w);
    *(uint2*)(y + i) = p;
    return;
  }
  const int idx = bid - 4096;
  const int z = idx >> 6;
  const float* W = z == 0 ? w0 : z == 1 ? w1 : z == 2 ? w2 : w3;
  unsigned short* WT = z == 0 ? o0 : z == 1 ? o1 : z == 2 ? o2 : o3;
  const int r0 = ((idx >> 3) & 7) * 64, c0 = (idx & 7) * 64;
  const int tr = threadIdx.x >> 4;
  const int tc = threadIdx.x & 15;
  #pragma unroll
  for (int i = 0; i < 4; i++) {
    int r = tr + i * 16;
    float4 v = *(const float4*)(W + (size_t)(r0 + r) * 512 + c0 + tc * 4);
    tle[r][tc * 4 + 0] = v.x;
    tle[r][tc * 4 + 1] = v.y;
    tle[r][tc * 4 + 2] = v.z;
    tle[r][tc * 4 + 3] = v.w;
  }
  __syncthreads();
  #pragma unroll
  for (int i = 0; i < 4; i++) {
    int c = tr + i * 16;
    int rr = tc * 4;
    uint2 p;
    p.x = packbf(tle[rr + 0][c], tle[rr + 1][c]);
    p.y = packbf(tle[rr + 2][c], tle[rr + 3][c]);
    *(uint2*)(WT + (size_t)(c0 + c) * 512 + r0 + rr) = p;
  }
}

// ---------------------------------------------------------------------------
// 64x128-tile bf16 MFMA GEMM core, BK=64, 4 waves (R8, unchanged).
// ---------------------------------------------------------------------------
__device__ __forceinline__ void gemm_core_bk64(const unsigned short* __restrict__ A,
                                               const unsigned short* __restrict__ BT,
                                               unsigned short* smem, int m0, int n0,
                                               int w, int lane, f32x16 (&acc)[2]) {
  unsigned short* Asm = smem;            // 2 buf x 4096 ushorts
  unsigned short* Bsm = smem + 8192;     // 2 buf x 8192 ushorts
  const int l31 = lane & 31, lh = lane >> 5;

  auto stage = [&](int kt, int buf) {
    const int k0 = kt * 64;
    #pragma unroll
    for (int i = 0; i < 2; i++) {
      int r = w * 2 + i, g = r >> 2, ks = r & 3;
      async16(A + (size_t)(m0 + g * 32 + l31) * 512 + k0 + ks * 16 + lh * 8,
              Asm + buf * 4096 + r * 512);
    }
    #pragma unroll
    for (int i = 0; i < 4; i++) {
      int r = w * 4 + i, gn = r >> 2, ks = r & 3;
      async16(BT + (size_t)(n0 + gn * 32 + l31) * 512 + k0 + ks * 16 + lh * 8,
              Bsm + buf * 8192 + r * 512);
    }
  };

  stage(0, 0);
  for (int kt = 0; kt < 8; ++kt) {
    __syncthreads();
    if (kt + 1 < 8) stage(kt + 1, (kt + 1) & 1);
    const int buf = kt & 1;
    const unsigned short* as = Asm + buf * 4096 + (w & 1) * 2048;
    const unsigned short* bs = Bsm + buf * 8192 + (w >> 1) * 4096;
    #pragma unroll
    for (int ks = 0; ks < 4; ++ks) {
      s16x8 af = *(const s16x8*)(as + ks * 512 + lane * 8);
      s16x8 b0 = *(const s16x8*)(bs + ks * 512 + lane * 8);
      s16x8 b1 = *(const s16x8*)(bs + 2048 + ks * 512 + lane * 8);
      acc[0] = MFMA32(af, b0, acc[0]);
      acc[1] = MFMA32(af, b1, acc[1]);
    }
  }
}

// ---------------------------------------------------------------------------
// Fused Q/K/V projection GEMM (R8, unchanged). grid (4, 64, 3).
// ---------------------------------------------------------------------------
__global__ __launch_bounds__(256) void gemm_qkv(const unsigned short* __restrict__ frB,
                                                const unsigned short* __restrict__ dtB,
                                                const unsigned short* __restrict__ WqT,
                                                const unsigned short* __restrict__ WkT,
                                                const unsigned short* __restrict__ WvT,
                                                unsigned short* __restrict__ Qp,
                                                unsigned short* __restrict__ Kp,
                                                unsigned short* __restrict__ VTp) {
  __shared__ __align__(16) unsigned short smem[24576];
  const int tid = threadIdx.x, lane = tid & 63, w = tid >> 6;
  const int l31 = lane & 31, lh = lane >> 5;
  const int m0 = blockIdx.y * 64, n0 = blockIdx.x * 128;
  const int z = blockIdx.z;
  const unsigned short* A = z == 0 ? frB : dtB;
  const unsigned short* BT = z == 0 ? WqT : (z == 1 ? WkT : WvT);
  unsigned short* OP = z == 0 ? Qp : (z == 1 ? Kp : VTp);
  const float scale = z == 0 ? QSCALE : 1.0f;

  f32x16 acc[2];
  #pragma unroll
  for (int j = 0; j < 2; j++)
    #pragma unroll
    for (int r = 0; r < 16; r++) acc[j][r] = 0.f;

  gemm_core_bk64(A, BT, smem, m0, n0, w, lane, acc);

  const int wm = (w & 1) * 32, wn = (w >> 1) * 64;
  const int bb = m0 >> 11, s0 = m0 & 2047;
  __syncthreads();
  if (z <= 1) {
    #pragma unroll
    for (int j = 0; j < 2; j++)
      #pragma unroll
      for (int r = 0; r < 16; r++) {
        int mm = wm + (r & 3) + 8 * (r >> 2) + 4 * lh;
        int nn = wn + j * 32 + l31;
        smem[mm * 136 + nn] = bfr(acc[j][r] * scale);
      }
    __syncthreads();
    #pragma unroll
    for (int it = 0; it < 4; ++it) {
      int c = tid + it * 256;
      int mm = c >> 4, seg = c & 15;
      uint4 vdat = *(const uint4*)(smem + mm * 136 + seg * 8);
      int n = n0 + seg * 8, h = n >> 6, d = n & 63;
      *(uint4*)(OP + ((size_t)((bb * NHEAD + h) * SEQ + s0 + mm)) * HD + d) = vdat;
    }
  } else {
    #pragma unroll
    for (int j = 0; j < 2; j++)
      #pragma unroll
      for (int r = 0; r < 16; r += 2) {
        int mm = wm + (r & 3) + 8 * (r >> 2) + 4 * lh;  // even
        int nn = wn + j * 32 + l31;
        *(unsigned int*)(smem + nn * 72 + mm) = packbf(acc[j][r], acc[j][r + 1]);
      }
    __syncthreads();
    #pragma unroll
    for (int it = 0; it < 4; ++it) {
      int c = tid + it * 256;
      int nn = c >> 3, seg = c & 7;
      uint4 vdat = *(const uint4*)(smem + nn * 72 + seg * 8);
      int n = n0 + nn, h = n >> 6, d = n & 63;
      *(uint4*)(OP + ((size_t)((bb * NHEAD + h) * HD + d)) * SEQ + s0 + seg * 8) = vdat;
    }
  }
}

// ---------------------------------------------------------------------------
// Final projection (R8, unchanged): out = aoB @ WoT^T + bias, fp32 out.
// ---------------------------------------------------------------------------
__global__ __launch_bounds__(256) void gemm_out(const unsigned short* __restrict__ A,
                                                const unsigned short* __restrict__ BT,
                                                const float* __restrict__ bias,
                                                float* __restrict__ O) {
  __shared__ __align__(16) unsigned short smem[24576];
  const int tid = threadIdx.x, lane = tid & 63, w = tid >> 6;
  const int l31 = lane & 31, lh = lane >> 5;
  const int m0 = blockIdx.y * 64, n0 = blockIdx.x * 128;

  f32x16 acc[2];
  #pragma unroll
  for (int j = 0; j < 2; j++)
    #pragma unroll
    for (int r = 0; r < 16; r++) acc[j][r] = 0.f;

  gemm_core_bk64(A, BT, smem, m0, n0, w, lane, acc);

  const int wm = (w & 1) * 32, wn = (w >> 1) * 64;
  #pragma unroll
  for (int j = 0; j < 2; j++) {
    float bv = bias[n0 + wn + j * 32 + l31];
    #pragma unroll
    for (int r = 0; r < 16; r++) {
      int mm = wm + (r & 3) + 8 * (r >> 2) + 4 * lh;
      O[(size_t)(m0 + mm) * 512 + n0 + wn + j * 32 + l31] = acc[j][r] + bv;
    }
  }
}

// ---------------------------------------------------------------------------
// MFMA flash attention — barrier-free K-loop via wave-private LDS staging
// with EXPLICIT vmcnt pipelining (fix of R9's races):
//   issue next slot's DMAs -> s_waitcnt vmcnt(#just-issued) -> read current.
// Block = 256 thr = 4 waves; each wave: all 64 q x its private 512-key
// quarter; 16 KB private arena, double-buffered. __syncthreads only in the
// end merges (5 total). XCD swizzle keeps K/V L2-resident (R8: ~7 MB fetch).
// ---------------------------------------------------------------------------
__global__ __launch_bounds__(256, 2) void attn_mfma(const unsigned short* __restrict__ Q,
                                                    const unsigned short* __restrict__ K,
                                                    const unsigned short* __restrict__ VT,
                                                    unsigned short* __restrict__ O) {
  __shared__ __align__(16) unsigned short arena[4][8192];  // 16 KB per wave
  __shared__ float larr[4][64];
  __shared__ float warr[4][64];

  const int tid = threadIdx.x;
  const int lane = tid & 63;
  const int w = tid >> 6;          // wave id = key quarter
  const int l31 = lane & 31, lh = lane >> 5;

  // XCD swizzle: pin 2 bh per XCD
  const int bid = blockIdx.x;
  const int g = bid & 7, j = bid >> 3;
  const int bh = g * 2 + (j >> 5);
  const int qt = j & 31;

  const unsigned short* Qh = Q + (size_t)bh * SEQ * HD;
  const unsigned short* Kh = K + (size_t)bh * SEQ * HD;
  const unsigned short* VTh = VT + (size_t)bh * HD * SEQ;

  // Q B-fragments: both 32-q subtiles (pre-scaled by 0.125*log2e)
  s16x8 qf[2][4];
  #pragma unroll
  for (int q2 = 0; q2 < 2; q2++)
    #pragma unroll
    for (int t = 0; t < 4; t++)
      qf[q2][t] = *(const s16x8*)(Qh + (size_t)(qt * 64 + q2 * 32 + l31) * HD + 16 * t + 8 * lh);

  unsigned short* kbuf = &arena[w][0];     // 2 x 2048 ushorts
  unsigned short* vbuf = &arena[w][4096];  // 2 x 2048 ushorts
  const int kbase = w * 512;

  auto stageK = [&](int c, int slot) {
    const unsigned short* base = Kh + (size_t)(kbase + c * 32 + l31) * HD + lh * 8;
    #pragma unroll
    for (int tt = 0; tt < 4; tt++)
      async16(base + tt * 16, kbuf + slot * 2048 + tt * 512);
  };
  auto stageV = [&](int c, int slot) {
    #pragma unroll
    for (int dh = 0; dh < 2; dh++)
      #pragma unroll
      for (int kc = 0; kc < 2; kc++)
        async16(VTh + (size_t)(dh * 32 + l31) * SEQ + kbase + c * 32 + kc * 16 + lh * 8,
                vbuf + slot * 2048 + (dh * 2 + kc) * 512);
  };

  // ---------------- sweep 1: per-q l = sum(exp2(s)), barrier-free --------
  float lsum[2] = {0.f, 0.f};
  stageK(0, 0);
  for (int c = 0; c < 16; ++c) {
    const int slot = c & 1;
    if (c + 1 < 16) {
      stageK(c + 1, slot ^ 1);
      SB0();
      WAITVM4();   // current slot's 4 DMAs landed; next slot's 4 in flight
      SB0();
    } else {
      SB0();
      WAITVM0();
      SB0();
    }
    s16x8 kf[4];
    #pragma unroll
    for (int tt = 0; tt < 4; tt++)
      kf[tt] = *(const s16x8*)(kbuf + slot * 2048 + tt * 512 + lane * 8);
    #pragma unroll
    for (int q2 = 0; q2 < 2; q2++) {
      f32x16 sc;
      #pragma unroll
      for (int r = 0; r < 16; r++) sc[r] = 0.f;
      #pragma unroll
      for (int tt = 0; tt < 4; tt++) sc = MFMA32(kf[tt], qf[q2][tt], sc);
      float s0 = 0.f, s1 = 0.f, s2 = 0.f, s3 = 0.f;
      #pragma unroll
      for (int r = 0; r < 4; r++) {
        s0 += EXP2(sc[r]);
        s1 += EXP2(sc[4 + r]);
        s2 += EXP2(sc[8 + r]);
        s3 += EXP2(sc[12 + r]);
      }
      lsum[q2] += (s0 + s1) + (s2 + s3);
    }
  }
  #pragma unroll
  for (int q2 = 0; q2 < 2; q2++) lsum[q2] += __shfl_xor(lsum[q2], 32);
  if (lh == 0) { larr[w][l31] = lsum[0]; larr[w][32 + l31] = lsum[1]; }
  __syncthreads();
  float tl[2];
  #pragma unroll
  for (int q2 = 0; q2 < 2; q2++)
    tl[q2] = ATT_T * (larr[0][q2 * 32 + l31] + larr[1][q2 * 32 + l31] +
                      larr[2][q2 * 32 + l31] + larr[3][q2 * 32 + l31]);

  // ---------------- sweep 2: clip + PV, barrier-free ----------------
  f32x16 acc[2][2];  // [qtile][dhalf]
  #pragma unroll
  for (int q2 = 0; q2 < 2; q2++)
    #pragma unroll
    for (int dh = 0; dh < 2; dh++)
      #pragma unroll
      for (int r = 0; r < 16; r++) acc[q2][dh][r] = 0.f;
  float wacc[2] = {0.f, 0.f};

  stageK(0, 0);
  stageV(0, 0);
  for (int c = 0; c < 16; ++c) {
    const int slot = c & 1;
    if (c + 1 < 16) {
      stageK(c + 1, slot ^ 1);
      stageV(c + 1, slot ^ 1);
      SB0();
      WAITVM8();   // current slot's 8 DMAs landed; next slot's 8 in flight
      SB0();
    } else {
      SB0();
      WAITVM0();
      SB0();
    }
    s16x8 kf[4], vf[2][2];
    #pragma unroll
    for (int tt = 0; tt < 4; tt++)
      kf[tt] = *(const s16x8*)(kbuf + slot * 2048 + tt * 512 + lane * 8);
    #pragma unroll
    for (int dh = 0; dh < 2; dh++)
      #pragma unroll
      for (int kc = 0; kc < 2; kc++)
        vf[dh][kc] = *(const s16x8*)(vbuf + slot * 2048 + (dh * 2 + kc) * 512 + lane * 8);
    s16x8 pf[2][2];
    #pragma unroll
    for (int q2 = 0; q2 < 2; q2++) {
      f32x16 sc;
      #pragma unroll
      for (int r = 0; r < 16; r++) sc[r] = 0.f;
      #pragma unroll
      for (int tt = 0; tt < 4; tt++) sc = MFMA32(kf[tt], qf[q2][tt], sc);
      uint2 quads[4];
      #pragma unroll
      for (int gq = 0; gq < 4; gq++) {
        float u0 = fmaxf(EXP2(sc[4 * gq + 0]) - tl[q2], 0.f);
        float u1 = fmaxf(EXP2(sc[4 * gq + 1]) - tl[q2], 0.f);
        float u2 = fmaxf(EXP2(sc[4 * gq + 2]) - tl[q2], 0.f);
        float u3 = fmaxf(EXP2(sc[4 * gq + 3]) - tl[q2], 0.f);
        wacc[q2] += (u0 + u1) + (u2 + u3);
        quads[gq].x = packbf(u0, u1);
        quads[gq].y = packbf(u2, u3);
      }
      #pragma unroll
      for (int tp = 0; tp < 2; tp++) {
        uint2 ea, eb;
        ea.x = (unsigned)__shfl_xor((int)quads[2 * tp].x, 32);
        ea.y = (unsigned)__shfl_xor((int)quads[2 * tp].y, 32);
        eb.x = (unsigned)__shfl_xor((int)quads[2 * tp + 1].x, 32);
        eb.y = (unsigned)__shfl_xor((int)quads[2 * tp + 1].y, 32);
        uint4 fr;
        if (lh == 0) { fr.x = quads[2 * tp].x; fr.y = quads[2 * tp].y; fr.z = ea.x; fr.w = ea.y; }
        else         { fr.x = eb.x; fr.y = eb.y; fr.z = quads[2 * tp + 1].x; fr.w = quads[2 * tp + 1].y; }
        pf[q2][tp] = __builtin_bit_cast(s16x8, fr);
      }
    }
    #pragma unroll
    for (int q2 = 0; q2 < 2; q2++)
      #pragma unroll
      for (int dh = 0; dh < 2; dh++) {
        acc[q2][dh] = MFMA32(pf[q2][0], vf[dh][0], acc[q2][dh]);
        acc[q2][dh] = MFMA32(pf[q2][1], vf[dh][1], acc[q2][dh]);
      }
  }

  // ---------------- cross-wave merge + output ----------------
  #pragma unroll
  for (int q2 = 0; q2 < 2; q2++) wacc[q2] += __shfl_xor(wacc[q2], 32);
  if (lh == 0) { warr[w][l31] = wacc[0]; warr[w][32 + l31] = wacc[1]; }
  __syncthreads();  // ALL waves done with staging arena -> safe to reuse

  float* plane0 = (float*)&arena[0][0];   // 16 KB (arena[0..1])
  float* plane1 = (float*)&arena[2][0];   // 16 KB (arena[2..3])

  if (w >= 2) {
    float* pl = (w == 2) ? plane0 : plane1;
    #pragma unroll
    for (int q2 = 0; q2 < 2; q2++)
      #pragma unroll
      for (int dh = 0; dh < 2; dh++)
        #pragma unroll
        for (int r = 0; r < 16; r++) {
          int ql = q2 * 32 + (r & 3) + 8 * (r >> 2) + 4 * lh;
          pl[ql * 64 + dh * 32 + l31] = acc[q2][dh][r];
        }
  }
  __syncthreads();
  if (w < 2) {
    float* pl = (w == 0) ? plane0 : plane1;
    #pragma unroll
    for (int q2 = 0; q2 < 2; q2++)
      #pragma unroll
      for (int dh = 0; dh < 2; dh++)
        #pragma unroll
        for (int r = 0; r < 16; r++) {
          int ql = q2 * 32 + (r & 3) + 8 * (r >> 2) + 4 * lh;
          acc[q2][dh][r] += pl[ql * 64 + dh * 32 + l31];
        }
  }
  __syncthreads();
  if (w == 1) {
    #pragma unroll
    for (int q2 = 0; q2 < 2; q2++)
      #pragma unroll
      for (int dh = 0; dh < 2; dh++)
        #pragma unroll
        for (int r = 0; r < 16; r++) {
          int ql = q2 * 32 + (r & 3) + 8 * (r >> 2) + 4 * lh;
          plane0[ql * 64 + dh * 32 + l31] = acc[q2][dh][r];
        }
  }
  __syncthreads();
  unsigned short* otile = &arena[2][0];  // 8 KB bf16 tile (plane1 area, done)
  if (w == 0) {
    #pragma unroll
    for (int q2 = 0; q2 < 2; q2++)
      #pragma unroll
      for (int dh = 0; dh < 2; dh++)
        #pragma unroll
        for (int r = 0; r < 16; r++) {
          int ql = q2 * 32 + (r & 3) + 8 * (r >> 2) + 4 * lh;
          float wt = warr[0][ql] + warr[1][ql] + warr[2][ql] + warr[3][ql];
          float v = (acc[q2][dh][r] + plane0[ql * 64 + dh * 32 + l31]) / wt;
          otile[ql * 64 + dh * 32 + l31] = bfr(v);
        }
  }
  __syncthreads();
  const int b = bh >> 3, h = bh & 7;
  #pragma unroll
  for (int it = 0; it < 2; ++it) {
    int c2 = tid + it * 256;
    int mm = c2 >> 3, seg = c2 & 7;
    uint4 vdat = *(const uint4*)(otile + mm * 64 + seg * 8);
    *(uint4*)(O + ((size_t)(b * SEQ + qt * 64 + mm)) * 512 + h * HD + seg * 8) = vdat;
  }
}

// ---------------------------------------------------------------------------
extern "C" void kernel_launch(void* const* d_in, const int* in_sizes, int n_in,
                              void* d_out, int out_size, void* d_ws, size_t ws_size,
                              hipStream_t stream) {
  const float* fr = (const float*)d_in[0];
  const float* dt = (const float*)d_in[1];
  const float* Wq = (const float*)d_in[2];
  const float* Wk = (const float*)d_in[3];
  const float* Wv = (const float*)d_in[4];
  const float* Wo = (const float*)d_in[5];
  const float* bo = (const float*)d_in[6];
  float* out = (float*)d_out;

  const size_t planeE = (size_t)BB * SEQ * 512;  // 2,097,152 elements
  const size_t wE = 512 * 512;
  unsigned short* p = (unsigned short*)d_ws;
  unsigned short* frB = p; p += planeE;
  unsigned short* dtB = p; p += planeE;
  unsigned short* WqT = p; p += wE;
  unsigned short* WkT = p; p += wE;
  unsigned short* WvT = p; p += wE;
  unsigned short* WoT = p; p += wE;
  unsigned short* Qp  = p; p += planeE;
  unsigned short* Kp  = p; p += planeE;
  unsigned short* VTp = p; p += planeE;
  unsigned short* aoB = p; p += planeE;

  prep<<<4352, 256, 0, stream>>>(fr, dt, Wq, Wk, Wv, Wo, frB, dtB, WqT, WkT, WvT, WoT);

  gemm_qkv<<<dim3(4, 64, 3), 256, 0, stream>>>(frB, dtB, WqT, WkT, WvT, Qp, Kp, VTp);

  attn_mfma<<<BB * NHEAD * 32, 256, 0, stream>>>(Qp, Kp, VTp, aoB);

  gemm_out<<<dim3(4, 64), 256, 0, stream>>>(aoB, WoT, bo, out);
}